// Round 3
// 1713.955 us; speedup vs baseline: 1.2411x; 1.2411x over previous
//
#include <hip/hip_runtime.h>
#include <hip/hip_bf16.h>
#include <stdint.h>

// ---------------- constants ----------------
#define M_TOK 4096      // TWO_B*SEQ = 8*512
#define NV    32000     // vocab
#define KH    4096      // hidden
#define KTILES 64       // KH / 64
#define IGNORE_INDEX (-100)

// fallback (old 128x128) kernel constants
#define BM    128
#define BN    128
#define BK    64
#define NBLK_OLD  (NV / BN)     // 250
#define MBLK_OLD  (M_TOK / BM)  // 32

typedef __bf16 bf16;
typedef bf16  bf16x8 __attribute__((ext_vector_type(8)));
typedef bf16  bf16x4 __attribute__((ext_vector_type(4)));
typedef float f32x4  __attribute__((ext_vector_type(4)));

__device__ __forceinline__ void async_copy16(const void* g, void* l) {
    __builtin_amdgcn_global_load_lds(
        (const __attribute__((address_space(1))) void*)g,
        (__attribute__((address_space(3))) void*)l, 16, 0, 0);
}

// ---------------- fp32 -> bf16 convert ----------------
__global__ __launch_bounds__(256) void cvt_bf16_kernel(const float* __restrict__ src,
                                                       bf16* __restrict__ dst, int n4) {
    int i = blockIdx.x * blockDim.x + threadIdx.x;
    int stride = gridDim.x * blockDim.x;
    const float4* s4 = (const float4*)src;
    bf16x4* d4 = (bf16x4*)dst;
    for (; i < n4; i += stride) {
        float4 v = s4[i];
        bf16x4 o;
        o[0] = (bf16)v.x; o[1] = (bf16)v.y; o[2] = (bf16)v.z; o[3] = (bf16)v.w;
        d4[i] = o;
    }
}

// ---------------- target logit: full fp32 dot per token ----------------
__global__ __launch_bounds__(256) void tlogit_kernel(const float* __restrict__ inp,
                                                     const float* __restrict__ W,
                                                     const float* __restrict__ bias,
                                                     const int* __restrict__ target,
                                                     float* __restrict__ tlogit) {
    const int wave = threadIdx.x >> 6, lane = threadIdx.x & 63;
    const int t = blockIdx.x * 4 + wave;
    if (t >= M_TOK) return;
    int tg = target[t];
    int row = (tg == IGNORE_INDEX) ? 0 : tg;
    const float4* a4 = (const float4*)(inp + (long)t * KH);
    const float4* w4 = (const float4*)(W + (long)row * KH);
    float acc = 0.f;
#pragma unroll
    for (int i = 0; i < 16; i++) {
        float4 a = a4[i * 64 + lane];
        float4 w = w4[i * 64 + lane];
        acc += a.x * w.x + a.y * w.y + a.z * w.z + a.w * w.w;
    }
#pragma unroll
    for (int d = 1; d < 64; d <<= 1) acc += __shfl_xor(acc, d, 64);
    if (lane == 0) tlogit[t] = acc + bias[row];
}

// =====================================================================
// 256x256 tile, BK=64, 8 waves (2M x 4N), 8-phase schedule with counted
// vmcnt (T3+T4), setprio around MFMA clusters (T5), XOR-swizzled LDS (T2),
// XCD-chunked block swizzle (T1). Each wave owns a 128x64 C sub-tile
// (8x4 fragments of 16x16). Per K-tile: 4 phases, quadrant order
// Q(0,0) Q(0,1) Q(1,1) Q(1,0); ds_reads per phase: 12/4/8/0.
// Staging (2 loads per half-tile): P0 -> (t+1).A-h1 into other buf;
// P2 -> (t+2).B-h0; P3 -> (t+2).B-h1 + (t+2).A-h0 into current buf.
// vmcnt(6) once per K-tile (3 halves in flight), vmcnt(0) only at tail.
// =====================================================================
__global__ __launch_bounds__(512, 2) void gemm_lse256_kernel(
    const bf16* __restrict__ A, const bf16* __restrict__ W16,
    const float* __restrict__ bias, float* __restrict__ pm, float* __restrict__ ps)
{
    __shared__ __align__(16) char smem[131072];   // 2 bufs x (A 32KB + B 32KB)
    const int tid = threadIdx.x;
    const int lane = tid & 63;
    const int wid = tid >> 6;
    const int wm = wid >> 2, wn = wid & 3;

    // XCD-chunked bijective swizzle: 2000 % 8 == 0
    const int bx = blockIdx.x;
    const int wg = (bx & 7) * 250 + (bx >> 3);
    const int nblk = wg >> 4;       // 0..124 (16 consecutive wg share one W panel)
    const int mblk = wg & 15;       // 0..15
    const int m0 = mblk << 8;
    const int n0 = nblk << 8;

    // staging: pre-swizzled global source (chunk = slot ^ row&7), linear LDS dst
    const int srow = tid >> 3, slot = tid & 7;
    const int chunk = slot ^ (srow & 7);
    const bf16* aSrc = A   + (size_t)(m0 + srow) * KH + chunk * 8;
    const bf16* bSrc = W16 + (size_t)(n0 + srow) * KH + chunk * 8;
    char* dA0 = smem +      0 + tid * 16;
    char* dB0 = smem +  32768 + tid * 16;
    char* dA1 = smem +  65536 + tid * 16;
    char* dB1 = smem +  98304 + tid * 16;

#define STG_A(DST, h, tt) do { if ((tt) < KTILES) {                            \
        const bf16* _s = aSrc + (size_t)(h) * 128 * KH + (size_t)(tt) * 64;    \
        async_copy16(_s,                   (DST) + (h) * 16384);               \
        async_copy16(_s + (size_t)64 * KH, (DST) + (h) * 16384 + 8192); } } while (0)
#define STG_B(DST, h, tt) do { if ((tt) < KTILES) {                            \
        const bf16* _s = bSrc + (size_t)(h) * 128 * KH + (size_t)(tt) * 64;    \
        async_copy16(_s,                   (DST) + (h) * 16384);               \
        async_copy16(_s + (size_t)64 * KH, (DST) + (h) * 16384 + 8192); } } while (0)

    // fragment read addressing (swizzled): row r, k-chunk c -> elem (c ^ (r&7))*8
    const int rA = wm * 128 + (lane & 15);
    const int rB = wn * 64  + (lane & 15);
    const int co0 = ((((lane >> 4) + 0) ^ (lane & 7)) << 3);
    const int co1 = ((((lane >> 4) + 4) ^ (lane & 7)) << 3);

    const bf16* sA[2] = { (const bf16*)(smem),         (const bf16*)(smem + 65536) };
    const bf16* sB[2] = { (const bf16*)(smem + 32768), (const bf16*)(smem + 98304) };

    f32x4 acc[8][4] = {};
    bf16x8 regA[8], regB0[4], regB1[4];

#define MFMA_Q(MB, NB, BR)                                                      \
    _Pragma("unroll")                                                           \
    for (int mt = 0; mt < 4; ++mt)                                              \
        _Pragma("unroll")                                                       \
        for (int nt = 0; nt < 2; ++nt)                                          \
            _Pragma("unroll")                                                   \
            for (int ks = 0; ks < 2; ++ks)                                      \
                acc[(MB) + mt][(NB) + nt] = __builtin_amdgcn_mfma_f32_16x16x32_bf16( \
                    regA[mt * 2 + ks], BR[nt * 2 + ks], acc[(MB) + mt][(NB) + nt], 0, 0, 0);

#define TILE_BODY(b, t, DA_O, DB_C, DA_C) do {                                  \
    /* ---- P0: Q(0,0) ---- */                                                  \
    _Pragma("unroll") for (int mt = 0; mt < 4; ++mt) {                          \
        regA[mt * 2]     = *(const bf16x8*)(sA[b] + (rA + mt * 16) * 64 + co0); \
        regA[mt * 2 + 1] = *(const bf16x8*)(sA[b] + (rA + mt * 16) * 64 + co1); } \
    _Pragma("unroll") for (int nt = 0; nt < 2; ++nt) {                          \
        regB0[nt * 2]     = *(const bf16x8*)(sB[b] + (rB + nt * 16) * 64 + co0); \
        regB0[nt * 2 + 1] = *(const bf16x8*)(sB[b] + (rB + nt * 16) * 64 + co1); } \
    STG_A(DA_O, 1, (t) + 1);                                                    \
    __builtin_amdgcn_s_barrier();                                               \
    asm volatile("s_waitcnt lgkmcnt(0)" ::: "memory");                          \
    __builtin_amdgcn_sched_barrier(0);                                          \
    __builtin_amdgcn_s_setprio(1);                                              \
    MFMA_Q(0, 0, regB0)                                                         \
    __builtin_amdgcn_s_setprio(0);                                              \
    __builtin_amdgcn_s_barrier();                                               \
    /* ---- P1: Q(0,1) ---- */                                                  \
    _Pragma("unroll") for (int nt = 0; nt < 2; ++nt) {                          \
        regB1[nt * 2]     = *(const bf16x8*)(sB[b] + (rB + (nt + 2) * 16) * 64 + co0); \
        regB1[nt * 2 + 1] = *(const bf16x8*)(sB[b] + (rB + (nt + 2) * 16) * 64 + co1); } \
    __builtin_amdgcn_s_barrier();                                               \
    asm volatile("s_waitcnt lgkmcnt(0)" ::: "memory");                          \
    __builtin_amdgcn_sched_barrier(0);                                          \
    __builtin_amdgcn_s_setprio(1);                                              \
    MFMA_Q(0, 2, regB1)                                                         \
    __builtin_amdgcn_s_setprio(0);                                              \
    __builtin_amdgcn_s_barrier();                                               \
    /* ---- P2: Q(1,1) ---- */                                                  \
    _Pragma("unroll") for (int mt = 0; mt < 4; ++mt) {                          \
        regA[mt * 2]     = *(const bf16x8*)(sA[b] + (rA + (mt + 4) * 16) * 64 + co0); \
        regA[mt * 2 + 1] = *(const bf16x8*)(sA[b] + (rA + (mt + 4) * 16) * 64 + co1); } \
    STG_B(DB_C, 0, (t) + 2);                                                    \
    __builtin_amdgcn_s_barrier();                                               \
    asm volatile("s_waitcnt lgkmcnt(0)" ::: "memory");                          \
    __builtin_amdgcn_sched_barrier(0);                                          \
    __builtin_amdgcn_s_setprio(1);                                              \
    MFMA_Q(4, 2, regB1)                                                         \
    __builtin_amdgcn_s_setprio(0);                                              \
    __builtin_amdgcn_s_barrier();                                               \
    /* ---- P3: Q(1,0) ---- */                                                  \
    STG_B(DB_C, 1, (t) + 2);                                                    \
    STG_A(DA_C, 0, (t) + 2);                                                    \
    __builtin_amdgcn_s_barrier();                                               \
    __builtin_amdgcn_s_setprio(1);                                              \
    MFMA_Q(4, 0, regB0)                                                         \
    __builtin_amdgcn_s_setprio(0);                                              \
    if ((t) + 2 < KTILES) { asm volatile("s_waitcnt vmcnt(6)" ::: "memory"); }  \
    else                  { asm volatile("s_waitcnt vmcnt(0)" ::: "memory"); }  \
    __builtin_amdgcn_s_barrier();                                               \
} while (0)

    // prologue: tile0 (4 halves) + tile1 {B-h0, B-h1, A-h0} -> 14 loads in flight
    STG_A(dA0, 0, 0); STG_A(dA0, 1, 0);
    STG_B(dB0, 0, 0); STG_B(dB0, 1, 0);
    STG_B(dB1, 0, 1); STG_B(dB1, 1, 1);
    STG_A(dA1, 0, 1);
    asm volatile("s_waitcnt vmcnt(6)" ::: "memory");   // tile0 fully landed
    __builtin_amdgcn_s_barrier();

#pragma unroll 1
    for (int t = 0; t < KTILES; t += 2) {
        TILE_BODY(0, t,     dA1, dB0, dA0);
        TILE_BODY(1, t + 1, dA0, dB1, dA1);
    }

    // ---- epilogue: bias add + per-row (max, sumexp) over this block's 256 cols ----
    float bv[4];
#pragma unroll
    for (int nt = 0; nt < 4; ++nt)
        bv[nt] = bias[n0 + wn * 64 + nt * 16 + (lane & 15)];

    float (*red_m)[256] = (float (*)[256])(smem);          // reuse LDS (all drained)
    float (*red_s)[256] = (float (*)[256])(smem + 4096);

#pragma unroll
    for (int mt = 0; mt < 8; ++mt) {
        float rm[4], rs[4];
#pragma unroll
        for (int r = 0; r < 4; ++r) {
            float v0 = acc[mt][0][r] + bv[0];
            float v1 = acc[mt][1][r] + bv[1];
            float v2 = acc[mt][2][r] + bv[2];
            float v3 = acc[mt][3][r] + bv[3];
            float mx = fmaxf(fmaxf(v0, v1), fmaxf(v2, v3));
#pragma unroll
            for (int d = 1; d < 16; d <<= 1) mx = fmaxf(mx, __shfl_xor(mx, d, 64));
            float s = __expf(v0 - mx) + __expf(v1 - mx) + __expf(v2 - mx) + __expf(v3 - mx);
#pragma unroll
            for (int d = 1; d < 16; d <<= 1) s += __shfl_xor(s, d, 64);
            rm[r] = mx; rs[r] = s;
        }
        if ((lane & 15) == 0) {
            int rl = wm * 128 + mt * 16 + (lane >> 4) * 4;
#pragma unroll
            for (int r = 0; r < 4; ++r) {
                red_m[wn][rl + r] = rm[r];
                red_s[wn][rl + r] = rs[r];
            }
        }
    }
    __syncthreads();
    if (tid < 256) {
        float mm = red_m[0][tid], ss = red_s[0][tid];
#pragma unroll
        for (int j = 1; j < 4; ++j) {
            float mj = red_m[j][tid], sj = red_s[j][tid];
            float m2 = fmaxf(mm, mj);
            ss = ss * __expf(mm - m2) + sj * __expf(mj - m2);
            mm = m2;
        }
        size_t idx = (size_t)nblk * M_TOK + m0 + tid;
        pm[idx] = mm;
        ps[idx] = ss;
    }
#undef TILE_BODY
#undef MFMA_Q
#undef STG_A
#undef STG_B
}

// ---------------- fallback: old 128x128 fused GEMM (f32 W, reg-convert) ----------------
template<bool PRECONV>
__global__ __launch_bounds__(256) void gemm_lse_kernel(const bf16* __restrict__ A,
                                                       const void* __restrict__ Wv,
                                                       const float* __restrict__ bias,
                                                       float* __restrict__ pm,
                                                       float* __restrict__ ps) {
    const int tid = threadIdx.x;
    const int wave = tid >> 6, lane = tid & 63;
    const int wm = wave & 1, wn = wave >> 1;
    const int bx = blockIdx.x;
    const int mblk = bx & 31;
    const int nblk = bx >> 5;
    const int m0 = mblk * BM, n0 = nblk * BN;

    __shared__ bf16 sA[BM * BK];
    __shared__ bf16 sB[BN * BK];
    __shared__ float red_m[2][BM];
    __shared__ float red_s[2][BM];

    f32x4 acc[4][4] = {};

    const int srow  = tid >> 3;
    const int slot  = tid & 7;
    const int chunk = slot ^ (srow & 7);
    const bf16* aptr = A + (long)(m0 + srow) * KH + chunk * 8;
    bf16* sA_dst = sA + tid * 8;
    bf16* sB_dst = sB + tid * 8;

    const bf16*  Wb = (const bf16*)Wv;
    const float* Wf = (const float*)Wv;
    const bf16*  bptr16 = Wb + (long)(n0 + srow) * KH + chunk * 8;
    const float* bptr32 = Wf + (long)(n0 + srow) * KH + chunk * 8;

    for (int k0 = 0; k0 < KH; k0 += BK) {
#pragma unroll
        for (int i = 0; i < 4; i++)
            async_copy16(aptr + (long)i * 32 * KH + k0, sA_dst + i * 2048);
        if (PRECONV) {
#pragma unroll
            for (int i = 0; i < 4; i++)
                async_copy16(bptr16 + (long)i * 32 * KH + k0, sB_dst + i * 2048);
        } else {
#pragma unroll
            for (int i = 0; i < 4; i++) {
                const float* wp = bptr32 + (long)i * 32 * KH + k0;
                float4 w0 = *(const float4*)(wp);
                float4 w1 = *(const float4*)(wp + 4);
                bf16x8 b;
                b[0] = (bf16)w0.x; b[1] = (bf16)w0.y; b[2] = (bf16)w0.z; b[3] = (bf16)w0.w;
                b[4] = (bf16)w1.x; b[5] = (bf16)w1.y; b[6] = (bf16)w1.z; b[7] = (bf16)w1.w;
                *(bf16x8*)(sB + (i * 32 + srow) * BK + slot * 8) = b;
            }
        }
        __syncthreads();
#pragma unroll
        for (int kk = 0; kk < BK; kk += 32) {
            bf16x8 af[4], bfr[4];
            const int rbase = wm * 64 + (lane & 15);
            const int cbase = wn * 64 + (lane & 15);
            const int c = (kk >> 3) + (lane >> 4);
            const int xoff = ((c ^ (lane & 7)) << 3);
#pragma unroll
            for (int t = 0; t < 4; t++)
                af[t] = *(const bf16x8*)(sA + (rbase + t * 16) * BK + xoff);
#pragma unroll
            for (int t = 0; t < 4; t++)
                bfr[t] = *(const bf16x8*)(sB + (cbase + t * 16) * BK + xoff);
#pragma unroll
            for (int mt = 0; mt < 4; mt++)
#pragma unroll
                for (int nt = 0; nt < 4; nt++)
                    acc[mt][nt] = __builtin_amdgcn_mfma_f32_16x16x32_bf16(
                        af[mt], bfr[nt], acc[mt][nt], 0, 0, 0);
        }
        __syncthreads();
    }

    float bv[4];
#pragma unroll
    for (int nt = 0; nt < 4; nt++)
        bv[nt] = bias[n0 + wn * 64 + nt * 16 + (lane & 15)];

#pragma unroll
    for (int mt = 0; mt < 4; mt++) {
        float rm[4], rs[4];
#pragma unroll
        for (int r = 0; r < 4; r++) {
            float v0 = acc[mt][0][r] + bv[0];
            float v1 = acc[mt][1][r] + bv[1];
            float v2 = acc[mt][2][r] + bv[2];
            float v3 = acc[mt][3][r] + bv[3];
            float mx = fmaxf(fmaxf(v0, v1), fmaxf(v2, v3));
#pragma unroll
            for (int d = 1; d < 16; d <<= 1) mx = fmaxf(mx, __shfl_xor(mx, d, 64));
            float s = __expf(v0 - mx) + __expf(v1 - mx) + __expf(v2 - mx) + __expf(v3 - mx);
#pragma unroll
            for (int d = 1; d < 16; d <<= 1) s += __shfl_xor(s, d, 64);
            rm[r] = mx; rs[r] = s;
        }
        if ((lane & 15) == 0) {
            int rl = wm * 64 + mt * 16 + (lane >> 4) * 4;
#pragma unroll
            for (int r = 0; r < 4; r++) {
                red_m[wn][rl + r] = rm[r];
                red_s[wn][rl + r] = rs[r];
            }
        }
    }
    __syncthreads();
    if (tid < BM) {
        float m0v = red_m[0][tid], s0v = red_s[0][tid];
        float m1v = red_m[1][tid], s1v = red_s[1][tid];
        float mm = fmaxf(m0v, m1v);
        float ss = s0v * __expf(m0v - mm) + s1v * __expf(m1v - mm);
        long idx = (long)nblk * M_TOK + m0 + tid;
        pm[idx] = mm;
        ps[idx] = ss;
    }
}

// ---------------- combine partials -> per-token logp ----------------
__global__ __launch_bounds__(256) void lse_combine_kernel(const float* __restrict__ pm,
                                                          const float* __restrict__ ps,
                                                          const float* __restrict__ tlogit,
                                                          const int* __restrict__ target,
                                                          float* __restrict__ per_tok,
                                                          int nblkN) {
    int t = blockIdx.x * blockDim.x + threadIdx.x;
    if (t >= M_TOK) return;
    float m = -1e30f, s = 0.f;
    for (int j = 0; j < nblkN; j++) {
        float mj = pm[j * M_TOK + t];
        float sj = ps[j * M_TOK + t];
        if (mj > m) {
            s = s * expf(m - mj) + sj;
            m = mj;
        } else {
            s += sj * expf(mj - m);
        }
    }
    float lse = m + logf(s);
    int tg = target[t];
    per_tok[t] = (tg != IGNORE_INDEX) ? (tlogit[t] - lse) : 0.0f;
}

// ---------------- final scalar loss ----------------
__global__ __launch_bounds__(512) void final_kernel(const float* __restrict__ per_tok,
                                                    const int* __restrict__ target,
                                                    const float* __restrict__ refc,
                                                    const float* __restrict__ refr,
                                                    float* __restrict__ out) {
    __shared__ float ssum[8];
    __shared__ float scnt[8];
    const int w = threadIdx.x >> 6, lane = threadIdx.x & 63;
    float sum = 0.f, cnt = 0.f;
#pragma unroll
    for (int i = 0; i < 8; i++) {
        int t = w * 512 + i * 64 + lane;
        sum += per_tok[t];
        cnt += (target[t] != IGNORE_INDEX) ? 1.f : 0.f;
    }
#pragma unroll
    for (int d = 1; d < 64; d <<= 1) {
        sum += __shfl_xor(sum, d, 64);
        cnt += __shfl_xor(cnt, d, 64);
    }
    if (lane == 0) { ssum[w] = sum; scnt[w] = cnt; }
    __syncthreads();
    if (threadIdx.x == 0) {
        float avg[8];
#pragma unroll
        for (int i = 0; i < 8; i++) avg[i] = ssum[i] / scnt[i];
        float nll_num = 0.f, nll_den = 0.f;
#pragma unroll
        for (int i = 0; i < 4; i++) { nll_num += ssum[i]; nll_den += scnt[i]; }
        float nll = -nll_num / nll_den;
        float pref = 0.f;
#pragma unroll
        for (int i = 0; i < 4; i++) {
            float x = 0.1f * ((avg[i] - refc[i]) - (avg[i + 4] - refr[i]));
            float ls = (x >= 0.f) ? -log1pf(expf(-x)) : (x - log1pf(expf(x)));
            pref += -ls;
        }
        pref *= 0.25f;
        out[0] = pref + nll;
    }
}

// ---------------- launch ----------------
extern "C" void kernel_launch(void* const* d_in, const int* in_sizes, int n_in,
                              void* d_out, int out_size, void* d_ws, size_t ws_size,
                              hipStream_t stream) {
    const float* W    = (const float*)d_in[0];  // [32000][4096]
    const float* inp  = (const float*)d_in[1];  // [8][512][4096]
    const int*   tgt  = (const int*)d_in[2];    // [8][512]
    const float* refc = (const float*)d_in[3];  // [4]
    const float* refr = (const float*)d_in[4];  // [4]
    const float* bias = (const float*)d_in[5];  // [32000]
    float* out = (float*)d_out;

    char* ws = (char*)d_ws;
    size_t off = 0;
    bf16* A16 = (bf16*)(ws + off); off += (size_t)M_TOK * KH * sizeof(bf16);         // 32 MB
    float* pm = (float*)(ws + off); off += (size_t)NBLK_OLD * M_TOK * sizeof(float); // 4 MB
    float* ps = (float*)(ws + off); off += (size_t)NBLK_OLD * M_TOK * sizeof(float); // 4 MB
    float* tl = (float*)(ws + off); off += (size_t)M_TOK * sizeof(float);
    float* ptk = (float*)(ws + off); off += (size_t)M_TOK * sizeof(float);
    bf16* W16 = (bf16*)(ws + off);
    size_t need = off + (size_t)NV * KH * sizeof(bf16);                              // +262 MB

    cvt_bf16_kernel<<<4096, 256, 0, stream>>>(inp, A16, (M_TOK * KH) / 4);
    tlogit_kernel<<<M_TOK / 4, 256, 0, stream>>>(inp, W, bias, tgt, tl);
    if (ws_size >= need) {
        cvt_bf16_kernel<<<16384, 256, 0, stream>>>(W, W16, (int)(((size_t)NV * KH) / 4));
        gemm_lse256_kernel<<<16 * 125, 512, 0, stream>>>(A16, W16, bias, pm, ps);
        lse_combine_kernel<<<(M_TOK + 255) / 256, 256, 0, stream>>>(pm, ps, tl, tgt, ptk, 125);
    } else {
        gemm_lse_kernel<false><<<MBLK_OLD * NBLK_OLD, 256, 0, stream>>>(A16, (const void*)W, bias, pm, ps);
        lse_combine_kernel<<<(M_TOK + 255) / 256, 256, 0, stream>>>(pm, ps, tl, tgt, ptk, NBLK_OLD);
    }
    final_kernel<<<1, 512, 0, stream>>>(ptk, tgt, refc, refr, out);
}